// Round 10
// baseline (503.349 us; speedup 1.0000x reference)
//
#include <hip/hip_runtime.h>
#include <hip/hip_bf16.h>

typedef short s16x8 __attribute__((ext_vector_type(8)));
typedef float f32x4 __attribute__((ext_vector_type(4)));
typedef float f32x2 __attribute__((ext_vector_type(2)));

#define MFMA_BF16(A, B, C) __builtin_amdgcn_mfma_f32_16x16x32_bf16(A, B, C, 0, 0, 0)

constexpr int Bn = 4, Tn = 2048, Cn = 1024, Hn = 16, Dn = 64;
constexpr int Mn = Bn * Tn;      // 8192
constexpr int Nqkv = 3 * Cn;     // 3072
constexpr float SC = 0.125f * 1.44269504089f;  // 1/sqrt(D) * log2(e)

__device__ __forceinline__ ushort f2bfu(float f) {
    __hip_bfloat16 h = __float2bfloat16(f);
    return *reinterpret_cast<ushort*>(&h);
}
__device__ __forceinline__ uint pkbf(float a, float b) {
    __hip_bfloat162 h = __float22bfloat162_rn(make_float2(a, b));
    return *reinterpret_cast<uint*>(&h);
}

// packed fp32 VALU (full-rate on CDNA4)
__device__ __forceinline__ f32x2 pk_add(f32x2 a, f32x2 b) {
    f32x2 d; asm("v_pk_add_f32 %0, %1, %2" : "=v"(d) : "v"(a), "v"(b)); return d;
}
__device__ __forceinline__ f32x2 pk_mul(f32x2 a, f32x2 b) {
    f32x2 d; asm("v_pk_mul_f32 %0, %1, %2" : "=v"(d) : "v"(a), "v"(b)); return d;
}

// async global->LDS, 16B per lane; LDS dest = wave-uniform base + lane*16.
__device__ __forceinline__ void gl_lds16(const void* g, void* l) {
    __builtin_amdgcn_global_load_lds(
        (const __attribute__((address_space(1))) void*)(uintptr_t)g,
        (__attribute__((address_space(3))) void*)(uint32_t)(uintptr_t)l,
        16, 0, 0);
}

// ---------------------------------------------------------------------------
// fp32 -> bf16 elementwise (x)
// ---------------------------------------------------------------------------
__global__ __launch_bounds__(256) void conv_bf16_kernel(
    const float* __restrict__ src, ushort* __restrict__ dst, int n4)
{
    int i = blockIdx.x * blockDim.x + threadIdx.x;
    int stride = gridDim.x * blockDim.x;
    for (; i < n4; i += stride) {
        float4 v = ((const float4*)src)[i];
        ushort4 o;
        o.x = f2bfu(v.x); o.y = f2bfu(v.y); o.z = f2bfu(v.z); o.w = f2bfu(v.w);
        ((ushort4*)dst)[i] = o;
    }
}

// ---------------------------------------------------------------------------
// W [K][N] fp32  ->  Wt [N][K] bf16   (64x64 tiles via LDS)
// ---------------------------------------------------------------------------
__global__ __launch_bounds__(256) void transpose_cvt_kernel(
    const float* __restrict__ W, ushort* __restrict__ Wt, int K, int N)
{
    __shared__ __align__(16) float Ls[64][68];
    const int t = threadIdx.x;
    const int n0 = blockIdx.x * 64, k0 = blockIdx.y * 64;
#pragma unroll
    for (int p = 0; p < 4; ++p) {
        int r = (t >> 4) + p * 16;
        int c = (t & 15) * 4;
        *(float4*)&Ls[r][c] = *(const float4*)&W[(size_t)(k0 + r) * N + n0 + c];
    }
    __syncthreads();
    const int n = t >> 2;
    const int ks = (t & 3) * 16;
    union { ushort s[16]; uint4 u[2]; } tmp;
#pragma unroll
    for (int j = 0; j < 16; ++j) tmp.s[j] = f2bfu(Ls[ks + j][n]);
    uint4* dp = (uint4*)&Wt[(size_t)(n0 + n) * K + k0 + ks];
    dp[0] = tmp.u[0];
    dp[1] = tmp.u[1];
}

// ---------------------------------------------------------------------------
// QKV GEMM, 256x256 / 8-wave geometry (m201-style reuse), r8-proven schedule:
//  - wave tile 128x64 (acc[8][4]): 24 ds_read_b128 -> 64 MFMA per K-step
//    (44 FLOP/LDS-byte vs 33 for 64x64 tile; 2.7x fewer LDS bytes/FLOP/CU)
//  - counted-vmcnt 1-ahead double buffer, raw s_barrier (T3/T4, r8-verified):
//    8 gl_lds/wave/step; prologue 16 in flight; vmcnt(8) retires step s.
//  - same source-side XOR swizzle + fragment xs math as r8 (row = 64 elems).
//  - blocks column-pure: nblk<8 -> Q/K (standard orient), nblk>=8 -> V
//    (swapped orient, direct Vt [bh][d][t] store).
// ---------------------------------------------------------------------------
__global__ __launch_bounds__(512, 2) void qkv_gemm_mfma(
    const ushort* __restrict__ A, const ushort* __restrict__ Bt,
    const float* __restrict__ bias,
    ushort* __restrict__ Qo, ushort* __restrict__ Ko, ushort* __restrict__ Vo)
{
    __shared__ __align__(16) ushort As[2][256 * 64];   // 64KB
    __shared__ __align__(16) ushort Bs[2][256 * 64];   // 64KB
    const int tid = threadIdx.x;                // 0..511
    const int bid = blockIdx.x;                 // 0..383
    const int mblk = bid / 12, nblk = bid % 12;
    const int m0 = mblk * 256, n0 = nblk * 256;
    const int w = tid >> 6;                     // 0..7
    const int lane = tid & 63, l15 = lane & 15, qd = lane >> 4;
    const int wm = (w >> 2) * 128;              // 2 m-halves of 128
    const int wn = (w & 3) * 64;                // 4 n-quarters of 64
    const int lrow = lane >> 3;
    const int lchunk = (lane & 7) ^ (lrow & 7);

    // staging: wave w stages rows w*32..w*32+31 of the 256-row A and B tiles
    const ushort* gA = A + (size_t)(m0 + w * 32 + lrow) * Cn + lchunk * 8;
    const ushort* gB = Bt + (size_t)(n0 + w * 32 + lrow) * Cn + lchunk * 8;

    f32x4 acc[8][4] = {};
    const bool isV = (n0 >= 2 * Cn);   // block-uniform

#define QSTAGE(s, b)                                                          \
    _Pragma("unroll")                                                         \
    for (int t_ = 0; t_ < 4; ++t_) {                                          \
        gl_lds16(gA + (size_t)t_ * 8 * Cn + (s) * 64,                         \
                 &As[b][(w * 32 + t_ * 8) * 64]);                             \
        gl_lds16(gB + (size_t)t_ * 8 * Cn + (s) * 64,                         \
                 &Bs[b][(w * 32 + t_ * 8) * 64]);                             \
    }

    QSTAGE(0, 0);
    QSTAGE(1, 1);

    for (int s = 0; s < 16; ++s) {
        if (s < 15) { asm volatile("s_waitcnt vmcnt(8)" ::: "memory"); }
        else        { asm volatile("s_waitcnt vmcnt(0)" ::: "memory"); }
        __builtin_amdgcn_sched_barrier(0);
        __builtin_amdgcn_s_barrier();        // step-s tile visible to all
        __builtin_amdgcn_sched_barrier(0);

        const ushort* a_ = As[s & 1];
        const ushort* b_ = Bs[s & 1];
        __builtin_amdgcn_s_setprio(1);
#pragma unroll
        for (int ks = 0; ks < 2; ++ks) {
            const int xs = (((ks * 4 + qd) ^ (l15 & 7))) * 8;
            s16x8 af[8], bfr[4];
#pragma unroll
            for (int i = 0; i < 8; ++i)
                af[i] = *(const s16x8*)&a_[(wm + i * 16 + l15) * 64 + xs];
#pragma unroll
            for (int i = 0; i < 4; ++i)
                bfr[i] = *(const s16x8*)&b_[(wn + i * 16 + l15) * 64 + xs];
            if (!isV) {
#pragma unroll
                for (int mt = 0; mt < 8; ++mt)
#pragma unroll
                    for (int nt = 0; nt < 4; ++nt)
                        acc[mt][nt] = MFMA_BF16(af[mt], bfr[nt], acc[mt][nt]);
            } else {
#pragma unroll
                for (int mt = 0; mt < 8; ++mt)
#pragma unroll
                    for (int nt = 0; nt < 4; ++nt)
                        acc[mt][nt] = MFMA_BF16(bfr[nt], af[mt], acc[mt][nt]);
            }
        }
        __builtin_amdgcn_s_setprio(0);

        __builtin_amdgcn_sched_barrier(0);
        __builtin_amdgcn_s_barrier();        // all waves done reading buf
        __builtin_amdgcn_sched_barrier(0);
        if (s + 2 < 16) { QSTAGE(s + 2, s & 1); }
    }
#undef QSTAGE

    if (!isV) {
        // ---- Q/K epilogue (standard orientation; acc[mt][nt] = C) ----
        const int sel = n0 >> 10;               // 0=Q, 1=K (uniform)
        ushort* O = (sel == 0) ? Qo : Ko;
        const float scl = (sel == 0) ? SC : 1.0f;
#pragma unroll
        for (int nt = 0; nt < 4; ++nt) {
            const int n_g = n0 + wn + nt * 16 + l15;
            const float bv = bias[n_g];
            const int h = (n_g >> 6) & 15;
            const int d = n_g & 63;
#pragma unroll
            for (int mt = 0; mt < 8; ++mt) {
#pragma unroll
                for (int r = 0; r < 4; ++r) {
                    const int m_g = m0 + wm + mt * 16 + qd * 4 + r;
                    const int b = m_g >> 11, t = m_g & 2047;
                    O[(((size_t)(b * Hn + h) * Tn + t) << 6) + d] =
                        f2bfu((acc[mt][nt][r] + bv) * scl);
                }
            }
        }
    } else {
        // ---- V epilogue: swapped orientation -> direct Vt [bh][d][t] ----
        // acc[mt][nt]: lane l15 -> t (m side), qd*4+j -> d (n side)
#pragma unroll
        for (int nt = 0; nt < 4; ++nt) {
            const int n_b = n0 + wn + nt * 16 + qd * 4;   // 4 consecutive d
            const float4 bv = *(const float4*)&bias[n_b];
            const int h = (n_b >> 6) & 15;
            const int d0 = n_b & 63;
#pragma unroll
            for (int mt = 0; mt < 8; ++mt) {
                const int m_g = m0 + wm + mt * 16 + l15;
                const int b = m_g >> 11, tt = m_g & 2047;
                const size_t rowb = (size_t)(b * Hn + h) * Dn;
                Vo[(rowb + d0 + 0) * Tn + tt] = f2bfu(acc[mt][nt][0] + bv.x);
                Vo[(rowb + d0 + 1) * Tn + tt] = f2bfu(acc[mt][nt][1] + bv.y);
                Vo[(rowb + d0 + 2) * Tn + tt] = f2bfu(acc[mt][nt][2] + bv.z);
                Vo[(rowb + d0 + 3) * Tn + tt] = f2bfu(acc[mt][nt][3] + bv.w);
            }
        }
    }
}

// ---------------------------------------------------------------------------
// MFMA flash attention (r5/r6, proven ~88us): async-DMA pipelined K/Vt LDS
// double-buffer, source-side swizzle, transposed-S, exp2 softmax, VALU-diet
// softmax (defer-max, packed f32, deferred l reduction), setprio on MFMA.
// ---------------------------------------------------------------------------
__global__ __launch_bounds__(256, 4) void attn_mfma(
    const ushort* __restrict__ Q, const ushort* __restrict__ K,
    const ushort* __restrict__ Vt, ushort* __restrict__ Y)
{
    __shared__ __align__(16) ushort Ks[2][64 * 64];
    __shared__ __align__(16) ushort Vs[2][64 * 64];
    __shared__ __align__(16) ushort Ps[64 * 64];

    const int tid = threadIdx.x;
    const int bh = blockIdx.x, bx = blockIdx.y;
    const int w = tid >> 6, lane = tid & 63, l15 = lane & 15, qd = lane >> 4;
    const size_t base = (size_t)bh * Tn * Dn;
    const int lrow = lane >> 3;                   // 0..7
    const int lchunk = (lane & 7) ^ (lrow & 7);   // source-side swizzle
    const int q_l = w * 16 + l15;
    const int frow = q_l * 64;
    const int fx0 = ((0 * 4 + qd) ^ (l15 & 7)) * 8;
    const int fx1 = ((1 * 4 + qd) ^ (l15 & 7)) * 8;
    const int b = bh >> 4, h = bh & 15;

    // staging sources: wave w stages rows w*16 .. w*16+15 of each tile
    const ushort* Kg = K + base + (size_t)(w * 16 + lrow) * Dn + lchunk * 8;
    const ushort* Vg = Vt + base + (size_t)(w * 16 + lrow) * Tn + lchunk * 8;
    // Q fragments direct from global
    const ushort* Qp = Q + base + (size_t)l15 * Dn + qd * 8;

#pragma unroll
    for (int half = 0; half < 2; ++half) {
        const int qt = half ? (31 - bx) : bx;

        const ushort* qrow = Qp + (size_t)(qt * 64 + w * 16) * Dn;
        s16x8 qf0 = *(const s16x8*)(qrow);
        s16x8 qf1 = *(const s16x8*)(qrow + 32);

        __syncthreads();   // previous half's LDS reads complete
        // issue DMA for tile 0 -> buffer 0
#pragma unroll
        for (int t = 0; t < 2; ++t) {
            gl_lds16(Kg + (size_t)(t * 8) * Dn, &Ks[0][(w * 16 + t * 8) * 64]);
            gl_lds16(Vg + (size_t)(t * 8) * Tn, &Vs[0][(w * 16 + t * 8) * 64]);
        }

        float m_run = -1e30f, l_run = 0.f;   // l_run: per-lane partial sum
        f32x4 o[4] = {};   // O^T[d=dt*16+qd*4+r][q=l15]

        for (int kt = 0; kt <= qt; ++kt) {
            const int buf = kt & 1;
            __syncthreads();   // drains own vmcnt -> tile kt ready; buf^1 free
            if (kt < qt) {     // issue DMA for kt+1 -> buf^1 (overlaps compute)
#pragma unroll
                for (int t = 0; t < 2; ++t) {
                    gl_lds16(Kg + (size_t)((kt + 1) * 64 + t * 8) * Dn,
                             &Ks[buf ^ 1][(w * 16 + t * 8) * 64]);
                    gl_lds16(Vg + (size_t)(t * 8) * Tn + (kt + 1) * 64,
                             &Vs[buf ^ 1][(w * 16 + t * 8) * 64]);
                }
            }

            // S^T = K·Q^T (exp2 domain via pre-scaled Q)
            f32x4 s[4] = {};
            __builtin_amdgcn_s_setprio(1);
#pragma unroll
            for (int nt = 0; nt < 4; ++nt) {
                s16x8 kf = *(const s16x8*)&Ks[buf][(nt * 16 + l15) * 64 + fx0];
                s[nt] = MFMA_BF16(kf, qf0, s[nt]);
            }
#pragma unroll
            for (int nt = 0; nt < 4; ++nt) {
                s16x8 kf = *(const s16x8*)&Ks[buf][(nt * 16 + l15) * 64 + fx1];
                s[nt] = MFMA_BF16(kf, qf1, s[nt]);
            }
            __builtin_amdgcn_s_setprio(0);

            if (kt == qt) {
#pragma unroll
                for (int nt = 0; nt < 4; ++nt)
#pragma unroll
                    for (int r = 0; r < 4; ++r)
                        if (nt * 16 + qd * 4 + r > q_l) s[nt][r] = -1e30f;
            }

            // per-query max: depth-4 tree (fuses to v_max3) + 2 shuffles
            float a0 = fmaxf(fmaxf(s[0][0], s[0][1]), fmaxf(s[0][2], s[0][3]));
            float a1 = fmaxf(fmaxf(s[1][0], s[1][1]), fmaxf(s[1][2], s[1][3]));
            float a2 = fmaxf(fmaxf(s[2][0], s[2][1]), fmaxf(s[2][2], s[2][3]));
            float a3 = fmaxf(fmaxf(s[3][0], s[3][1]), fmaxf(s[3][2], s[3][3]));
            float mx = fmaxf(fmaxf(a0, a1), fmaxf(a2, a3));
            mx = fmaxf(mx, __shfl_xor(mx, 16));
            mx = fmaxf(mx, __shfl_xor(mx, 32));

            // defer-max: only rescale when the max grew by > 8 (2^8 bound)
            if (!__all(mx <= m_run + 8.f)) {
                float m_new = fmaxf(m_run, mx);
                float alpha = exp2f(m_run - m_new);
                m_run = m_new;
                l_run *= alpha;
                f32x2 aa = {alpha, alpha};
#pragma unroll
                for (int dt = 0; dt < 4; ++dt) {
                    o[dt].lo = pk_mul(o[dt].lo, aa);
                    o[dt].hi = pk_mul(o[dt].hi, aa);
                }
            }

            // p = exp2(s - m_run); packed subtract / packed l-accum
            const f32x2 negm = {-m_run, -m_run};
            f32x2 lac0 = {0.f, 0.f}, lac1 = {0.f, 0.f};
#pragma unroll
            for (int nt = 0; nt < 4; ++nt) {
                s[nt].lo = pk_add(s[nt].lo, negm);
                s[nt].hi = pk_add(s[nt].hi, negm);
                s[nt][0] = exp2f(s[nt][0]);
                s[nt][1] = exp2f(s[nt][1]);
                s[nt][2] = exp2f(s[nt][2]);
                s[nt][3] = exp2f(s[nt][3]);
                lac0 = pk_add(lac0, s[nt].lo);
                lac1 = pk_add(lac1, s[nt].hi);
            }
            lac0 = pk_add(lac0, lac1);
            l_run += lac0[0] + lac0[1];

            // P^T -> wave-private LDS rows (packed bf16 pairs)
#pragma unroll
            for (int nt = 0; nt < 4; ++nt) {
                uint2 pk;
                pk.x = pkbf(s[nt][0], s[nt][1]);
                pk.y = pkbf(s[nt][2], s[nt][3]);
                const int pc = 2 * nt + (qd >> 1), po = (qd & 1) * 4;
                *(uint2*)&Ps[frow + ((pc ^ (l15 & 7)) * 8) + po] = pk;
            }

            // O^T += V^T · P^T  (same-wave LDS round trip; no barrier)
            {
                s16x8 pb = *(const s16x8*)&Ps[frow + fx0];
                __builtin_amdgcn_s_setprio(1);
#pragma unroll
                for (int dt = 0; dt < 4; ++dt) {
                    s16x8 vf = *(const s16x8*)&Vs[buf][(dt * 16 + l15) * 64 + fx0];
                    o[dt] = MFMA_BF16(vf, pb, o[dt]);
                }
                pb = *(const s16x8*)&Ps[frow + fx1];
#pragma unroll
                for (int dt = 0; dt < 4; ++dt) {
                    s16x8 vf = *(const s16x8*)&Vs[buf][(dt * 16 + l15) * 64 + fx1];
                    o[dt] = MFMA_BF16(vf, pb, o[dt]);
                }
                __builtin_amdgcn_s_setprio(0);
            }
        }

        // epilogue: reduce partial l across the 4-lane query group, then
        // O^T[d][q=l15] -> Y[b, t=q_global, h*64+d]
        float lt = l_run;
        lt += __shfl_xor(lt, 16);
        lt += __shfl_xor(lt, 32);
        const float inv = 1.f / lt;
        const int t_g = qt * 64 + w * 16 + l15;
        ushort* yp = Y + ((size_t)(b * Tn + t_g)) * Cn + h * Dn + qd * 4;
#pragma unroll
        for (int dt = 0; dt < 4; ++dt) {
            uint2 pk;
            pk.x = pkbf(o[dt][0] * inv, o[dt][1] * inv);
            pk.y = pkbf(o[dt][2] * inv, o[dt][3] * inv);
            *(uint2*)(yp + dt * 16) = pk;
        }
    }
}

// ---------------------------------------------------------------------------
// Pipelined GEMM staging macro (r8-proven) for proj.
// ---------------------------------------------------------------------------
#define GSTAGE(s, b)                                                          \
    _Pragma("unroll")                                                         \
    for (int t_ = 0; t_ < 4; ++t_) {                                          \
        gl_lds16(gA + (size_t)t_ * 8 * Cn + (s) * 64,                         \
                 &As[b][(w * 32 + t_ * 8) * 64]);                             \
        gl_lds16(gB + (size_t)t_ * 8 * Cn + (s) * 64,                         \
                 &Bs[b][(w * 32 + t_ * 8) * 64]);                             \
    }

// ---------------------------------------------------------------------------
// Proj GEMM, pipelined (r8 version, 2D grid): Y [8192][1024] bf16,
// Wt [1024][1024] bf16 -> out fp32
// ---------------------------------------------------------------------------
__global__ __launch_bounds__(256, 2) void proj_gemm_mfma(
    const ushort* __restrict__ A, const ushort* __restrict__ Bt,
    const float* __restrict__ bias, float* __restrict__ out)
{
    __shared__ __align__(16) ushort As[2][128 * 64];
    __shared__ __align__(16) ushort Bs[2][128 * 64];
    const int tid = threadIdx.x;
    const int m0 = blockIdx.x * 128, n0 = blockIdx.y * 128;
    const int w = tid >> 6, lane = tid & 63, l15 = lane & 15, qd = lane >> 4;
    const int wm = (w >> 1) * 64, wn = (w & 1) * 64;
    const int lrow = lane >> 3;
    const int lchunk = (lane & 7) ^ (lrow & 7);

    const ushort* gA = A + (size_t)(m0 + w * 32 + lrow) * Cn + lchunk * 8;
    const ushort* gB = Bt + (size_t)(n0 + w * 32 + lrow) * Cn + lchunk * 8;

    f32x4 acc[4][4] = {};

    GSTAGE(0, 0);
    GSTAGE(1, 1);

    for (int s = 0; s < 16; ++s) {
        if (s < 15) { asm volatile("s_waitcnt vmcnt(8)" ::: "memory"); }
        else        { asm volatile("s_waitcnt vmcnt(0)" ::: "memory"); }
        __builtin_amdgcn_sched_barrier(0);
        __builtin_amdgcn_s_barrier();
        __builtin_amdgcn_sched_barrier(0);

        const ushort* a_ = As[s & 1];
        const ushort* b_ = Bs[s & 1];
        __builtin_amdgcn_s_setprio(1);
#pragma unroll
        for (int ks = 0; ks < 2; ++ks) {
            const int xs = (((ks * 4 + qd) ^ (l15 & 7))) * 8;
            s16x8 af[4], bfr[4];
#pragma unroll
            for (int i = 0; i < 4; ++i) {
                af[i]  = *(const s16x8*)&a_[(wm + i * 16 + l15) * 64 + xs];
                bfr[i] = *(const s16x8*)&b_[(wn + i * 16 + l15) * 64 + xs];
            }
#pragma unroll
            for (int mt = 0; mt < 4; ++mt)
#pragma unroll
                for (int nt = 0; nt < 4; ++nt)
                    acc[mt][nt] = MFMA_BF16(af[mt], bfr[nt], acc[mt][nt]);
        }
        __builtin_amdgcn_s_setprio(0);

        __builtin_amdgcn_sched_barrier(0);
        __builtin_amdgcn_s_barrier();
        __builtin_amdgcn_sched_barrier(0);
        if (s + 2 < 16) { GSTAGE(s + 2, s & 1); }
    }

#pragma unroll
    for (int nt = 0; nt < 4; ++nt) {
        int n_g = n0 + wn + nt * 16 + l15;
        float bv = bias[n_g];
#pragma unroll
        for (int mt = 0; mt < 4; ++mt) {
#pragma unroll
            for (int r = 0; r < 4; ++r) {
                int m_g = m0 + wm + mt * 16 + qd * 4 + r;
                out[(size_t)m_g * Cn + n_g] = acc[mt][nt][r] + bv;
            }
        }
    }
}

// ---------------------------------------------------------------------------
extern "C" void kernel_launch(void* const* d_in, const int* in_sizes, int n_in,
                              void* d_out, int out_size, void* d_ws, size_t ws_size,
                              hipStream_t stream) {
    const float* x      = (const float*)d_in[0];
    const float* W_attn = (const float*)d_in[1];
    const float* b_attn = (const float*)d_in[2];
    const float* W_proj = (const float*)d_in[3];
    const float* b_proj = (const float*)d_in[4];
    float* out = (float*)d_out;

    // ws: Q, K [B,H,T,D] bf16; Vt [B,H,D,T] bf16 (written directly by qkv);
    //     Y [B,T,C] bf16
    constexpr size_t PER = (size_t)Mn * Cn;  // 8388608 elems
    ushort* Qb  = (ushort*)d_ws;
    ushort* Kb  = Qb + PER;
    ushort* Vtb = Kb + PER;
    ushort* Yb  = Vtb + PER;

    // d_out as scratch (33.5 MB): WtA [3072][1024] bf16 + x_bf [8192][1024] bf16
    ushort* WtA  = (ushort*)d_out;
    ushort* x_bf = WtA + (size_t)Nqkv * Cn;
    ushort* WtP  = Qb;                 // reuses Q buffer (dead after attention)

    conv_bf16_kernel<<<1024, 256, 0, stream>>>(x, x_bf, (int)(PER / 4));
    transpose_cvt_kernel<<<dim3(Nqkv / 64, Cn / 64), 256, 0, stream>>>(
        W_attn, WtA, Cn, Nqkv);
    qkv_gemm_mfma<<<(Mn / 256) * (Nqkv / 256), 512, 0, stream>>>(
        x_bf, WtA, b_attn, Qb, Kb, Vtb);
    attn_mfma<<<dim3(Bn * Hn, 16), 256, 0, stream>>>(Qb, Kb, Vtb, Yb);
    transpose_cvt_kernel<<<dim3(Cn / 64, Cn / 64), 256, 0, stream>>>(
        W_proj, WtP, Cn, Cn);
    proj_gemm_mfma<<<dim3(Mn / 128, Cn / 128), 256, 0, stream>>>(
        Yb, WtP, b_proj, out);
}

// Round 11
// 374.980 us; speedup vs baseline: 1.3423x; 1.3423x over previous
//
#include <hip/hip_runtime.h>
#include <hip/hip_bf16.h>

typedef short s16x8 __attribute__((ext_vector_type(8)));
typedef float f32x4 __attribute__((ext_vector_type(4)));
typedef float f32x2 __attribute__((ext_vector_type(2)));

#define MFMA_BF16(A, B, C) __builtin_amdgcn_mfma_f32_16x16x32_bf16(A, B, C, 0, 0, 0)

constexpr int Bn = 4, Tn = 2048, Cn = 1024, Hn = 16, Dn = 64;
constexpr int Mn = Bn * Tn;      // 8192
constexpr int Nqkv = 3 * Cn;     // 3072
constexpr float SC = 0.125f * 1.44269504089f;  // 1/sqrt(D) * log2(e)

__device__ __forceinline__ ushort f2bfu(float f) {
    __hip_bfloat16 h = __float2bfloat16(f);
    return *reinterpret_cast<ushort*>(&h);
}
__device__ __forceinline__ uint pkbf(float a, float b) {
    __hip_bfloat162 h = __float22bfloat162_rn(make_float2(a, b));
    return *reinterpret_cast<uint*>(&h);
}

// packed fp32 VALU (full-rate on CDNA4)
__device__ __forceinline__ f32x2 pk_add(f32x2 a, f32x2 b) {
    f32x2 d; asm("v_pk_add_f32 %0, %1, %2" : "=v"(d) : "v"(a), "v"(b)); return d;
}
__device__ __forceinline__ f32x2 pk_mul(f32x2 a, f32x2 b) {
    f32x2 d; asm("v_pk_mul_f32 %0, %1, %2" : "=v"(d) : "v"(a), "v"(b)); return d;
}

// async global->LDS, 16B per lane; LDS dest = wave-uniform base + lane*16.
__device__ __forceinline__ void gl_lds16(const void* g, void* l) {
    __builtin_amdgcn_global_load_lds(
        (const __attribute__((address_space(1))) void*)(uintptr_t)g,
        (__attribute__((address_space(3))) void*)(uint32_t)(uintptr_t)l,
        16, 0, 0);
}

// ---------------------------------------------------------------------------
// fp32 -> bf16 elementwise (x)
// ---------------------------------------------------------------------------
__global__ __launch_bounds__(256) void conv_bf16_kernel(
    const float* __restrict__ src, ushort* __restrict__ dst, int n4)
{
    int i = blockIdx.x * blockDim.x + threadIdx.x;
    int stride = gridDim.x * blockDim.x;
    for (; i < n4; i += stride) {
        float4 v = ((const float4*)src)[i];
        ushort4 o;
        o.x = f2bfu(v.x); o.y = f2bfu(v.y); o.z = f2bfu(v.z); o.w = f2bfu(v.w);
        ((ushort4*)dst)[i] = o;
    }
}

// ---------------------------------------------------------------------------
// W [K][N] fp32  ->  Wt [N][K] bf16   (64x64 tiles via LDS)
// ---------------------------------------------------------------------------
__global__ __launch_bounds__(256) void transpose_cvt_kernel(
    const float* __restrict__ W, ushort* __restrict__ Wt, int K, int N)
{
    __shared__ __align__(16) float Ls[64][68];
    const int t = threadIdx.x;
    const int n0 = blockIdx.x * 64, k0 = blockIdx.y * 64;
#pragma unroll
    for (int p = 0; p < 4; ++p) {
        int r = (t >> 4) + p * 16;
        int c = (t & 15) * 4;
        *(float4*)&Ls[r][c] = *(const float4*)&W[(size_t)(k0 + r) * N + n0 + c];
    }
    __syncthreads();
    const int n = t >> 2;
    const int ks = (t & 3) * 16;
    union { ushort s[16]; uint4 u[2]; } tmp;
#pragma unroll
    for (int j = 0; j < 16; ++j) tmp.s[j] = f2bfu(Ls[ks + j][n]);
    uint4* dp = (uint4*)&Wt[(size_t)(n0 + n) * K + k0 + ks];
    dp[0] = tmp.u[0];
    dp[1] = tmp.u[1];
}

// ---------------------------------------------------------------------------
// QKV GEMM, 256x256 / 8-wave geometry (r10 port, spill fixed):
//  - __launch_bounds__(512, 1): min 1 wave/EU lifts regalloc cap to full
//    budget (r10's (512,2) allocated 128 VGPR and spilled ~900MB to scratch;
//    acc[8][4] alone is 128 VGPR). LDS 128KB already caps at 1 block/CU
//    = 2 waves/SIMD, so the relaxed bound costs no occupancy.
//  - af fragment loaded INSIDE the mt loop (live set ~170 regs, not 190+).
//  - wave tile 128x64: 24 ds_read_b128 -> 64 MFMA per K-step (2.7x fewer
//    LDS bytes/FLOP/CU than the 128-tile; LDS-read was the binding pipe).
//  - counted-vmcnt 1-ahead double buffer, raw s_barrier (r8-proven audit:
//    8 gl_lds/wave/step; in flight at top of iter s = 16; vmcnt(8)).
//  - blocks column-pure: nblk<8 -> Q/K; nblk>=8 -> V (swapped orient,
//    direct Vt [bh][d][t] store). Correctness of both proven in r10.
// ---------------------------------------------------------------------------
__global__ __launch_bounds__(512, 1) void qkv_gemm_mfma(
    const ushort* __restrict__ A, const ushort* __restrict__ Bt,
    const float* __restrict__ bias,
    ushort* __restrict__ Qo, ushort* __restrict__ Ko, ushort* __restrict__ Vo)
{
    __shared__ __align__(16) ushort As[2][256 * 64];   // 64KB
    __shared__ __align__(16) ushort Bs[2][256 * 64];   // 64KB
    const int tid = threadIdx.x;                // 0..511
    const int bid = blockIdx.x;                 // 0..383
    const int mblk = bid / 12, nblk = bid % 12;
    const int m0 = mblk * 256, n0 = nblk * 256;
    const int w = tid >> 6;                     // 0..7
    const int lane = tid & 63, l15 = lane & 15, qd = lane >> 4;
    const int wm = (w >> 2) * 128;              // 2 m-halves of 128
    const int wn = (w & 3) * 64;                // 4 n-quarters of 64
    const int lrow = lane >> 3;
    const int lchunk = (lane & 7) ^ (lrow & 7);

    // staging: wave w stages rows w*32..w*32+31 of the 256-row A and B tiles
    const ushort* gA = A + (size_t)(m0 + w * 32 + lrow) * Cn + lchunk * 8;
    const ushort* gB = Bt + (size_t)(n0 + w * 32 + lrow) * Cn + lchunk * 8;

    f32x4 acc[8][4] = {};
    const bool isV = (n0 >= 2 * Cn);   // block-uniform

#define QSTAGE(s, b)                                                          \
    _Pragma("unroll")                                                         \
    for (int t_ = 0; t_ < 4; ++t_) {                                          \
        gl_lds16(gA + (size_t)t_ * 8 * Cn + (s) * 64,                         \
                 &As[b][(w * 32 + t_ * 8) * 64]);                             \
        gl_lds16(gB + (size_t)t_ * 8 * Cn + (s) * 64,                         \
                 &Bs[b][(w * 32 + t_ * 8) * 64]);                             \
    }

    QSTAGE(0, 0);
    QSTAGE(1, 1);

    for (int s = 0; s < 16; ++s) {
        if (s < 15) { asm volatile("s_waitcnt vmcnt(8)" ::: "memory"); }
        else        { asm volatile("s_waitcnt vmcnt(0)" ::: "memory"); }
        __builtin_amdgcn_sched_barrier(0);
        __builtin_amdgcn_s_barrier();        // step-s tile visible to all
        __builtin_amdgcn_sched_barrier(0);

        const ushort* a_ = As[s & 1];
        const ushort* b_ = Bs[s & 1];
        __builtin_amdgcn_s_setprio(1);
#pragma unroll
        for (int ks = 0; ks < 2; ++ks) {
            const int xs = (((ks * 4 + qd) ^ (l15 & 7))) * 8;
            s16x8 bfr[4];
#pragma unroll
            for (int i = 0; i < 4; ++i)
                bfr[i] = *(const s16x8*)&b_[(wn + i * 16 + l15) * 64 + xs];
            if (!isV) {
#pragma unroll
                for (int mt = 0; mt < 8; ++mt) {
                    s16x8 af = *(const s16x8*)&a_[(wm + mt * 16 + l15) * 64 + xs];
#pragma unroll
                    for (int nt = 0; nt < 4; ++nt)
                        acc[mt][nt] = MFMA_BF16(af, bfr[nt], acc[mt][nt]);
                }
            } else {
#pragma unroll
                for (int mt = 0; mt < 8; ++mt) {
                    s16x8 af = *(const s16x8*)&a_[(wm + mt * 16 + l15) * 64 + xs];
#pragma unroll
                    for (int nt = 0; nt < 4; ++nt)
                        acc[mt][nt] = MFMA_BF16(bfr[nt], af, acc[mt][nt]);
                }
            }
        }
        __builtin_amdgcn_s_setprio(0);

        __builtin_amdgcn_sched_barrier(0);
        __builtin_amdgcn_s_barrier();        // all waves done reading buf
        __builtin_amdgcn_sched_barrier(0);
        if (s + 2 < 16) { QSTAGE(s + 2, s & 1); }
    }
#undef QSTAGE

    if (!isV) {
        // ---- Q/K epilogue (standard orientation; acc[mt][nt] = C) ----
        const int sel = n0 >> 10;               // 0=Q, 1=K (uniform)
        ushort* O = (sel == 0) ? Qo : Ko;
        const float scl = (sel == 0) ? SC : 1.0f;
#pragma unroll
        for (int nt = 0; nt < 4; ++nt) {
            const int n_g = n0 + wn + nt * 16 + l15;
            const float bv = bias[n_g];
            const int h = (n_g >> 6) & 15;
            const int d = n_g & 63;
#pragma unroll
            for (int mt = 0; mt < 8; ++mt) {
#pragma unroll
                for (int r = 0; r < 4; ++r) {
                    const int m_g = m0 + wm + mt * 16 + qd * 4 + r;
                    const int b = m_g >> 11, t = m_g & 2047;
                    O[(((size_t)(b * Hn + h) * Tn + t) << 6) + d] =
                        f2bfu((acc[mt][nt][r] + bv) * scl);
                }
            }
        }
    } else {
        // ---- V epilogue: swapped orientation -> direct Vt [bh][d][t] ----
        // acc[mt][nt]: lane l15 -> t (m side), qd*4+j -> d (n side)
#pragma unroll
        for (int nt = 0; nt < 4; ++nt) {
            const int n_b = n0 + wn + nt * 16 + qd * 4;   // 4 consecutive d
            const float4 bv = *(const float4*)&bias[n_b];
            const int h = (n_b >> 6) & 15;
            const int d0 = n_b & 63;
#pragma unroll
            for (int mt = 0; mt < 8; ++mt) {
                const int m_g = m0 + wm + mt * 16 + l15;
                const int b = m_g >> 11, tt = m_g & 2047;
                const size_t rowb = (size_t)(b * Hn + h) * Dn;
                Vo[(rowb + d0 + 0) * Tn + tt] = f2bfu(acc[mt][nt][0] + bv.x);
                Vo[(rowb + d0 + 1) * Tn + tt] = f2bfu(acc[mt][nt][1] + bv.y);
                Vo[(rowb + d0 + 2) * Tn + tt] = f2bfu(acc[mt][nt][2] + bv.z);
                Vo[(rowb + d0 + 3) * Tn + tt] = f2bfu(acc[mt][nt][3] + bv.w);
            }
        }
    }
}

// ---------------------------------------------------------------------------
// MFMA flash attention (r5/r6, proven ~88us): async-DMA pipelined K/Vt LDS
// double-buffer, source-side swizzle, transposed-S, exp2 softmax, VALU-diet
// softmax (defer-max, packed f32, deferred l reduction), setprio on MFMA.
// ---------------------------------------------------------------------------
__global__ __launch_bounds__(256, 4) void attn_mfma(
    const ushort* __restrict__ Q, const ushort* __restrict__ K,
    const ushort* __restrict__ Vt, ushort* __restrict__ Y)
{
    __shared__ __align__(16) ushort Ks[2][64 * 64];
    __shared__ __align__(16) ushort Vs[2][64 * 64];
    __shared__ __align__(16) ushort Ps[64 * 64];

    const int tid = threadIdx.x;
    const int bh = blockIdx.x, bx = blockIdx.y;
    const int w = tid >> 6, lane = tid & 63, l15 = lane & 15, qd = lane >> 4;
    const size_t base = (size_t)bh * Tn * Dn;
    const int lrow = lane >> 3;                   // 0..7
    const int lchunk = (lane & 7) ^ (lrow & 7);   // source-side swizzle
    const int q_l = w * 16 + l15;
    const int frow = q_l * 64;
    const int fx0 = ((0 * 4 + qd) ^ (l15 & 7)) * 8;
    const int fx1 = ((1 * 4 + qd) ^ (l15 & 7)) * 8;
    const int b = bh >> 4, h = bh & 15;

    // staging sources: wave w stages rows w*16 .. w*16+15 of each tile
    const ushort* Kg = K + base + (size_t)(w * 16 + lrow) * Dn + lchunk * 8;
    const ushort* Vg = Vt + base + (size_t)(w * 16 + lrow) * Tn + lchunk * 8;
    // Q fragments direct from global
    const ushort* Qp = Q + base + (size_t)l15 * Dn + qd * 8;

#pragma unroll
    for (int half = 0; half < 2; ++half) {
        const int qt = half ? (31 - bx) : bx;

        const ushort* qrow = Qp + (size_t)(qt * 64 + w * 16) * Dn;
        s16x8 qf0 = *(const s16x8*)(qrow);
        s16x8 qf1 = *(const s16x8*)(qrow + 32);

        __syncthreads();   // previous half's LDS reads complete
        // issue DMA for tile 0 -> buffer 0
#pragma unroll
        for (int t = 0; t < 2; ++t) {
            gl_lds16(Kg + (size_t)(t * 8) * Dn, &Ks[0][(w * 16 + t * 8) * 64]);
            gl_lds16(Vg + (size_t)(t * 8) * Tn, &Vs[0][(w * 16 + t * 8) * 64]);
        }

        float m_run = -1e30f, l_run = 0.f;   // l_run: per-lane partial sum
        f32x4 o[4] = {};   // O^T[d=dt*16+qd*4+r][q=l15]

        for (int kt = 0; kt <= qt; ++kt) {
            const int buf = kt & 1;
            __syncthreads();   // drains own vmcnt -> tile kt ready; buf^1 free
            if (kt < qt) {     // issue DMA for kt+1 -> buf^1 (overlaps compute)
#pragma unroll
                for (int t = 0; t < 2; ++t) {
                    gl_lds16(Kg + (size_t)((kt + 1) * 64 + t * 8) * Dn,
                             &Ks[buf ^ 1][(w * 16 + t * 8) * 64]);
                    gl_lds16(Vg + (size_t)(t * 8) * Tn + (kt + 1) * 64,
                             &Vs[buf ^ 1][(w * 16 + t * 8) * 64]);
                }
            }

            // S^T = K·Q^T (exp2 domain via pre-scaled Q)
            f32x4 s[4] = {};
            __builtin_amdgcn_s_setprio(1);
#pragma unroll
            for (int nt = 0; nt < 4; ++nt) {
                s16x8 kf = *(const s16x8*)&Ks[buf][(nt * 16 + l15) * 64 + fx0];
                s[nt] = MFMA_BF16(kf, qf0, s[nt]);
            }
#pragma unroll
            for (int nt = 0; nt < 4; ++nt) {
                s16x8 kf = *(const s16x8*)&Ks[buf][(nt * 16 + l15) * 64 + fx1];
                s[nt] = MFMA_BF16(kf, qf1, s[nt]);
            }
            __builtin_amdgcn_s_setprio(0);

            if (kt == qt) {
#pragma unroll
                for (int nt = 0; nt < 4; ++nt)
#pragma unroll
                    for (int r = 0; r < 4; ++r)
                        if (nt * 16 + qd * 4 + r > q_l) s[nt][r] = -1e30f;
            }

            // per-query max: depth-4 tree (fuses to v_max3) + 2 shuffles
            float a0 = fmaxf(fmaxf(s[0][0], s[0][1]), fmaxf(s[0][2], s[0][3]));
            float a1 = fmaxf(fmaxf(s[1][0], s[1][1]), fmaxf(s[1][2], s[1][3]));
            float a2 = fmaxf(fmaxf(s[2][0], s[2][1]), fmaxf(s[2][2], s[2][3]));
            float a3 = fmaxf(fmaxf(s[3][0], s[3][1]), fmaxf(s[3][2], s[3][3]));
            float mx = fmaxf(fmaxf(a0, a1), fmaxf(a2, a3));
            mx = fmaxf(mx, __shfl_xor(mx, 16));
            mx = fmaxf(mx, __shfl_xor(mx, 32));

            // defer-max: only rescale when the max grew by > 8 (2^8 bound)
            if (!__all(mx <= m_run + 8.f)) {
                float m_new = fmaxf(m_run, mx);
                float alpha = exp2f(m_run - m_new);
                m_run = m_new;
                l_run *= alpha;
                f32x2 aa = {alpha, alpha};
#pragma unroll
                for (int dt = 0; dt < 4; ++dt) {
                    o[dt].lo = pk_mul(o[dt].lo, aa);
                    o[dt].hi = pk_mul(o[dt].hi, aa);
                }
            }

            // p = exp2(s - m_run); packed subtract / packed l-accum
            const f32x2 negm = {-m_run, -m_run};
            f32x2 lac0 = {0.f, 0.f}, lac1 = {0.f, 0.f};
#pragma unroll
            for (int nt = 0; nt < 4; ++nt) {
                s[nt].lo = pk_add(s[nt].lo, negm);
                s[nt].hi = pk_add(s[nt].hi, negm);
                s[nt][0] = exp2f(s[nt][0]);
                s[nt][1] = exp2f(s[nt][1]);
                s[nt][2] = exp2f(s[nt][2]);
                s[nt][3] = exp2f(s[nt][3]);
                lac0 = pk_add(lac0, s[nt].lo);
                lac1 = pk_add(lac1, s[nt].hi);
            }
            lac0 = pk_add(lac0, lac1);
            l_run += lac0[0] + lac0[1];

            // P^T -> wave-private LDS rows (packed bf16 pairs)
#pragma unroll
            for (int nt = 0; nt < 4; ++nt) {
                uint2 pk;
                pk.x = pkbf(s[nt][0], s[nt][1]);
                pk.y = pkbf(s[nt][2], s[nt][3]);
                const int pc = 2 * nt + (qd >> 1), po = (qd & 1) * 4;
                *(uint2*)&Ps[frow + ((pc ^ (l15 & 7)) * 8) + po] = pk;
            }

            // O^T += V^T · P^T  (same-wave LDS round trip; no barrier)
            {
                s16x8 pb = *(const s16x8*)&Ps[frow + fx0];
                __builtin_amdgcn_s_setprio(1);
#pragma unroll
                for (int dt = 0; dt < 4; ++dt) {
                    s16x8 vf = *(const s16x8*)&Vs[buf][(dt * 16 + l15) * 64 + fx0];
                    o[dt] = MFMA_BF16(vf, pb, o[dt]);
                }
                pb = *(const s16x8*)&Ps[frow + fx1];
#pragma unroll
                for (int dt = 0; dt < 4; ++dt) {
                    s16x8 vf = *(const s16x8*)&Vs[buf][(dt * 16 + l15) * 64 + fx1];
                    o[dt] = MFMA_BF16(vf, pb, o[dt]);
                }
                __builtin_amdgcn_s_setprio(0);
            }
        }

        // epilogue: reduce partial l across the 4-lane query group, then
        // O^T[d][q=l15] -> Y[b, t=q_global, h*64+d]
        float lt = l_run;
        lt += __shfl_xor(lt, 16);
        lt += __shfl_xor(lt, 32);
        const float inv = 1.f / lt;
        const int t_g = qt * 64 + w * 16 + l15;
        ushort* yp = Y + ((size_t)(b * Tn + t_g)) * Cn + h * Dn + qd * 4;
#pragma unroll
        for (int dt = 0; dt < 4; ++dt) {
            uint2 pk;
            pk.x = pkbf(o[dt][0] * inv, o[dt][1] * inv);
            pk.y = pkbf(o[dt][2] * inv, o[dt][3] * inv);
            *(uint2*)(yp + dt * 16) = pk;
        }
    }
}

// ---------------------------------------------------------------------------
// Pipelined GEMM staging macro (r8-proven) for proj.
// ---------------------------------------------------------------------------
#define GSTAGE(s, b)                                                          \
    _Pragma("unroll")                                                         \
    for (int t_ = 0; t_ < 4; ++t_) {                                          \
        gl_lds16(gA + (size_t)t_ * 8 * Cn + (s) * 64,                         \
                 &As[b][(w * 32 + t_ * 8) * 64]);                             \
        gl_lds16(gB + (size_t)t_ * 8 * Cn + (s) * 64,                         \
                 &Bs[b][(w * 32 + t_ * 8) * 64]);                             \
    }

// ---------------------------------------------------------------------------
// Proj GEMM, pipelined (r8 version, 2D grid): Y [8192][1024] bf16,
// Wt [1024][1024] bf16 -> out fp32
// ---------------------------------------------------------------------------
__global__ __launch_bounds__(256, 2) void proj_gemm_mfma(
    const ushort* __restrict__ A, const ushort* __restrict__ Bt,
    const float* __restrict__ bias, float* __restrict__ out)
{
    __shared__ __align__(16) ushort As[2][128 * 64];
    __shared__ __align__(16) ushort Bs[2][128 * 64];
    const int tid = threadIdx.x;
    const int m0 = blockIdx.x * 128, n0 = blockIdx.y * 128;
    const int w = tid >> 6, lane = tid & 63, l15 = lane & 15, qd = lane >> 4;
    const int wm = (w >> 1) * 64, wn = (w & 1) * 64;
    const int lrow = lane >> 3;
    const int lchunk = (lane & 7) ^ (lrow & 7);

    const ushort* gA = A + (size_t)(m0 + w * 32 + lrow) * Cn + lchunk * 8;
    const ushort* gB = Bt + (size_t)(n0 + w * 32 + lrow) * Cn + lchunk * 8;

    f32x4 acc[4][4] = {};

    GSTAGE(0, 0);
    GSTAGE(1, 1);

    for (int s = 0; s < 16; ++s) {
        if (s < 15) { asm volatile("s_waitcnt vmcnt(8)" ::: "memory"); }
        else        { asm volatile("s_waitcnt vmcnt(0)" ::: "memory"); }
        __builtin_amdgcn_sched_barrier(0);
        __builtin_amdgcn_s_barrier();
        __builtin_amdgcn_sched_barrier(0);

        const ushort* a_ = As[s & 1];
        const ushort* b_ = Bs[s & 1];
        __builtin_amdgcn_s_setprio(1);
#pragma unroll
        for (int ks = 0; ks < 2; ++ks) {
            const int xs = (((ks * 4 + qd) ^ (l15 & 7))) * 8;
            s16x8 af[4], bfr[4];
#pragma unroll
            for (int i = 0; i < 4; ++i) {
                af[i]  = *(const s16x8*)&a_[(wm + i * 16 + l15) * 64 + xs];
                bfr[i] = *(const s16x8*)&b_[(wn + i * 16 + l15) * 64 + xs];
            }
#pragma unroll
            for (int mt = 0; mt < 4; ++mt)
#pragma unroll
                for (int nt = 0; nt < 4; ++nt)
                    acc[mt][nt] = MFMA_BF16(af[mt], bfr[nt], acc[mt][nt]);
        }
        __builtin_amdgcn_s_setprio(0);

        __builtin_amdgcn_sched_barrier(0);
        __builtin_amdgcn_s_barrier();
        __builtin_amdgcn_sched_barrier(0);
        if (s + 2 < 16) { GSTAGE(s + 2, s & 1); }
    }

#pragma unroll
    for (int nt = 0; nt < 4; ++nt) {
        int n_g = n0 + wn + nt * 16 + l15;
        float bv = bias[n_g];
#pragma unroll
        for (int mt = 0; mt < 4; ++mt) {
#pragma unroll
            for (int r = 0; r < 4; ++r) {
                int m_g = m0 + wm + mt * 16 + qd * 4 + r;
                out[(size_t)m_g * Cn + n_g] = acc[mt][nt][r] + bv;
            }
        }
    }
}

// ---------------------------------------------------------------------------
extern "C" void kernel_launch(void* const* d_in, const int* in_sizes, int n_in,
                              void* d_out, int out_size, void* d_ws, size_t ws_size,
                              hipStream_t stream) {
    const float* x      = (const float*)d_in[0];
    const float* W_attn = (const float*)d_in[1];
    const float* b_attn = (const float*)d_in[2];
    const float* W_proj = (const float*)d_in[3];
    const float* b_proj = (const float*)d_in[4];
    float* out = (float*)d_out;

    // ws: Q, K [B,H,T,D] bf16; Vt [B,H,D,T] bf16 (written directly by qkv);
    //     Y [B,T,C] bf16
    constexpr size_t PER = (size_t)Mn * Cn;  // 8388608 elems
    ushort* Qb  = (ushort*)d_ws;
    ushort* Kb  = Qb + PER;
    ushort* Vtb = Kb + PER;
    ushort* Yb  = Vtb + PER;

    // d_out as scratch (33.5 MB): WtA [3072][1024] bf16 + x_bf [8192][1024] bf16
    ushort* WtA  = (ushort*)d_out;
    ushort* x_bf = WtA + (size_t)Nqkv * Cn;
    ushort* WtP  = Qb;                 // reuses Q buffer (dead after attention)

    conv_bf16_kernel<<<1024, 256, 0, stream>>>(x, x_bf, (int)(PER / 4));
    transpose_cvt_kernel<<<dim3(Nqkv / 64, Cn / 64), 256, 0, stream>>>(
        W_attn, WtA, Cn, Nqkv);
    qkv_gemm_mfma<<<(Mn / 256) * (Nqkv / 256), 512, 0, stream>>>(
        x_bf, WtA, b_attn, Qb, Kb, Vtb);
    attn_mfma<<<dim3(Bn * Hn, 16), 256, 0, stream>>>(Qb, Kb, Vtb, Yb);
    transpose_cvt_kernel<<<dim3(Cn / 64, Cn / 64), 256, 0, stream>>>(
        W_proj, WtP, Cn, Cn);
    proj_gemm_mfma<<<dim3(Mn / 128, Cn / 128), 256, 0, stream>>>(
        Yb, WtP, b_proj, out);
}

// Round 13
// 247.964 us; speedup vs baseline: 2.0299x; 1.5122x over previous
//
#include <hip/hip_runtime.h>
#include <hip/hip_bf16.h>

typedef short s16x8 __attribute__((ext_vector_type(8)));
typedef float f32x4 __attribute__((ext_vector_type(4)));
typedef float f32x2 __attribute__((ext_vector_type(2)));

#define MFMA_BF16(A, B, C) __builtin_amdgcn_mfma_f32_16x16x32_bf16(A, B, C, 0, 0, 0)

constexpr int Bn = 4, Tn = 2048, Cn = 1024, Hn = 16, Dn = 64;
constexpr int Mn = Bn * Tn;      // 8192
constexpr int Nqkv = 3 * Cn;     // 3072
constexpr float SC = 0.125f * 1.44269504089f;  // 1/sqrt(D) * log2(e)

__device__ __forceinline__ ushort f2bfu(float f) {
    __hip_bfloat16 h = __float2bfloat16(f);
    return *reinterpret_cast<ushort*>(&h);
}
__device__ __forceinline__ uint pkbf(float a, float b) {
    __hip_bfloat162 h = __float22bfloat162_rn(make_float2(a, b));
    return *reinterpret_cast<uint*>(&h);
}

// packed fp32 VALU (full-rate on CDNA4)
__device__ __forceinline__ f32x2 pk_add(f32x2 a, f32x2 b) {
    f32x2 d; asm("v_pk_add_f32 %0, %1, %2" : "=v"(d) : "v"(a), "v"(b)); return d;
}
__device__ __forceinline__ f32x2 pk_mul(f32x2 a, f32x2 b) {
    f32x2 d; asm("v_pk_mul_f32 %0, %1, %2" : "=v"(d) : "v"(a), "v"(b)); return d;
}

// async global->LDS, 16B per lane; LDS dest = wave-uniform base + lane*16.
__device__ __forceinline__ void gl_lds16(const void* g, void* l) {
    __builtin_amdgcn_global_load_lds(
        (const __attribute__((address_space(1))) void*)(uintptr_t)g,
        (__attribute__((address_space(3))) void*)(uint32_t)(uintptr_t)l,
        16, 0, 0);
}

// ---------------------------------------------------------------------------
// Prep kernel: fused {fp32->bf16 conv of x} + {W_attn transpose-convert}.
// Both memory-bound and independent; fusing removes one launch gap and
// overlaps their BW windows. Blocks 0..2047: conv; 2048..2815: transpose.
// ---------------------------------------------------------------------------
__global__ __launch_bounds__(256) void prep_kernel(
    const float* __restrict__ x, ushort* __restrict__ x_bf, int n4,
    const float* __restrict__ W, ushort* __restrict__ Wt)
{
    __shared__ __align__(16) float Ls[64][68];
    const int bid = blockIdx.x;
    if (bid < 2048) {
        int i = bid * 256 + threadIdx.x;
        const int stride = 2048 * 256;
        for (; i < n4; i += stride) {
            float4 v = ((const float4*)x)[i];
            ushort4 o;
            o.x = f2bfu(v.x); o.y = f2bfu(v.y); o.z = f2bfu(v.z); o.w = f2bfu(v.w);
            ((ushort4*)x_bf)[i] = o;
        }
    } else {
        const int tb = bid - 2048;                 // 0..767
        const int n0 = (tb >> 4) * 64;             // over N = 3072
        const int k0 = (tb & 15) * 64;             // over K = 1024
        const int t = threadIdx.x;
#pragma unroll
        for (int p = 0; p < 4; ++p) {
            int r = (t >> 4) + p * 16;
            int c = (t & 15) * 4;
            *(float4*)&Ls[r][c] =
                *(const float4*)&W[(size_t)(k0 + r) * Nqkv + n0 + c];
        }
        __syncthreads();
        const int n = t >> 2;
        const int ks = (t & 3) * 16;
        union { ushort s[16]; uint4 u[2]; } tmp;
#pragma unroll
        for (int j = 0; j < 16; ++j) tmp.s[j] = f2bfu(Ls[ks + j][n]);
        uint4* dp = (uint4*)&Wt[(size_t)(n0 + n) * Cn + k0 + ks];
        dp[0] = tmp.u[0];
        dp[1] = tmp.u[1];
    }
}

// ---------------------------------------------------------------------------
// W [K][N] fp32  ->  Wt [N][K] bf16   (64x64 tiles via LDS) — for W_proj
// ---------------------------------------------------------------------------
__global__ __launch_bounds__(256) void transpose_cvt_kernel(
    const float* __restrict__ W, ushort* __restrict__ Wt, int K, int N)
{
    __shared__ __align__(16) float Ls[64][68];
    const int t = threadIdx.x;
    const int n0 = blockIdx.x * 64, k0 = blockIdx.y * 64;
#pragma unroll
    for (int p = 0; p < 4; ++p) {
        int r = (t >> 4) + p * 16;
        int c = (t & 15) * 4;
        *(float4*)&Ls[r][c] = *(const float4*)&W[(size_t)(k0 + r) * N + n0 + c];
    }
    __syncthreads();
    const int n = t >> 2;
    const int ks = (t & 3) * 16;
    union { ushort s[16]; uint4 u[2]; } tmp;
#pragma unroll
    for (int j = 0; j < 16; ++j) tmp.s[j] = f2bfu(Ls[ks + j][n]);
    uint4* dp = (uint4*)&Wt[(size_t)(n0 + n) * K + k0 + ks];
    dp[0] = tmp.u[0];
    dp[1] = tmp.u[1];
}

// ---------------------------------------------------------------------------
// Pipelined GEMM main-loop building blocks (T3/T4, r8-proven): 1-ahead double
// buffer, counted vmcnt (never 0 in steady state), raw s_barrier.
// Per wave per K-step: 8 gl_lds (4 A + 4 B). In flight at top of iter s:
// steps {s, s+1} = 16 loads -> vmcnt(8) retires exactly step s (FIFO).
// ---------------------------------------------------------------------------
#define GSTAGE(s, b)                                                          \
    _Pragma("unroll")                                                         \
    for (int t_ = 0; t_ < 4; ++t_) {                                          \
        gl_lds16(gA + (size_t)t_ * 8 * Cn + (s) * 64,                         \
                 &As[b][(w * 32 + t_ * 8) * 64]);                             \
        gl_lds16(gB + (size_t)t_ * 8 * Cn + (s) * 64,                         \
                 &Bs[b][(w * 32 + t_ * 8) * 64]);                             \
    }

// ---------------------------------------------------------------------------
// QKV GEMM, pipelined (r8-proven, 128^2, no spill). Q pre-scaled by SC.
// Blocks column-pure: Q/K standard epilogue; V swapped-orientation epilogue
// writing directly into Vt [bh][d][t].
// ---------------------------------------------------------------------------
__global__ __launch_bounds__(256, 2) void qkv_gemm_mfma(
    const ushort* __restrict__ A, const ushort* __restrict__ Bt,
    const float* __restrict__ bias,
    ushort* __restrict__ Qo, ushort* __restrict__ Ko, ushort* __restrict__ Vo)
{
    __shared__ __align__(16) ushort As[2][128 * 64];   // 32KB
    __shared__ __align__(16) ushort Bs[2][128 * 64];   // 32KB
    const int tid = threadIdx.x;
    const int m0 = blockIdx.x * 128, n0 = blockIdx.y * 128;
    const int w = tid >> 6, lane = tid & 63, l15 = lane & 15, qd = lane >> 4;
    const int wm = (w >> 1) * 64, wn = (w & 1) * 64;
    const int lrow = lane >> 3;
    const int lchunk = (lane & 7) ^ (lrow & 7);

    const ushort* gA = A + (size_t)(m0 + w * 32 + lrow) * Cn + lchunk * 8;
    const ushort* gB = Bt + (size_t)(n0 + w * 32 + lrow) * Cn + lchunk * 8;

    f32x4 acc[4][4] = {};
    const bool isV = (n0 >= 2 * Cn);   // block-uniform

    GSTAGE(0, 0);
    GSTAGE(1, 1);

    for (int s = 0; s < 16; ++s) {
        if (s < 15) { asm volatile("s_waitcnt vmcnt(8)" ::: "memory"); }
        else        { asm volatile("s_waitcnt vmcnt(0)" ::: "memory"); }
        __builtin_amdgcn_sched_barrier(0);
        __builtin_amdgcn_s_barrier();        // (A) step-s tile visible to all
        __builtin_amdgcn_sched_barrier(0);

        const ushort* a_ = As[s & 1];
        const ushort* b_ = Bs[s & 1];
        __builtin_amdgcn_s_setprio(1);
#pragma unroll
        for (int ks = 0; ks < 2; ++ks) {
            const int xs = (((ks * 4 + qd) ^ (l15 & 7))) * 8;
            s16x8 af[4], bfr[4];
#pragma unroll
            for (int i = 0; i < 4; ++i) {
                af[i]  = *(const s16x8*)&a_[(wm + i * 16 + l15) * 64 + xs];
                bfr[i] = *(const s16x8*)&b_[(wn + i * 16 + l15) * 64 + xs];
            }
            if (!isV) {
#pragma unroll
                for (int mt = 0; mt < 4; ++mt)
#pragma unroll
                    for (int nt = 0; nt < 4; ++nt)
                        acc[mt][nt] = MFMA_BF16(af[mt], bfr[nt], acc[mt][nt]);
            } else {
#pragma unroll
                for (int mt = 0; mt < 4; ++mt)
#pragma unroll
                    for (int nt = 0; nt < 4; ++nt)
                        acc[nt][mt] = MFMA_BF16(bfr[nt], af[mt], acc[nt][mt]);
            }
        }
        __builtin_amdgcn_s_setprio(0);

        __builtin_amdgcn_sched_barrier(0);
        __builtin_amdgcn_s_barrier();        // (B) all waves done reading buf
        __builtin_amdgcn_sched_barrier(0);
        if (s + 2 < 16) { GSTAGE(s + 2, s & 1); }
    }

    if (!isV) {
        // ---- Q/K epilogue (standard orientation, r1/r6-proven) ----
        const int sel = n0 >> 10;               // 0=Q, 1=K (uniform)
        ushort* O = (sel == 0) ? Qo : Ko;
        const float scl = (sel == 0) ? SC : 1.0f;
#pragma unroll
        for (int nt = 0; nt < 4; ++nt) {
            const int n_g = n0 + wn + nt * 16 + l15;
            const float bv = bias[n_g];
            const int h = (n_g >> 6) & 15;
            const int d = n_g & 63;
#pragma unroll
            for (int mt = 0; mt < 4; ++mt) {
#pragma unroll
                for (int r = 0; r < 4; ++r) {
                    const int m_g = m0 + wm + mt * 16 + qd * 4 + r;
                    const int b = m_g >> 11, t = m_g & 2047;
                    O[(((size_t)(b * Hn + h) * Tn + t) << 6) + d] =
                        f2bfu((acc[mt][nt][r] + bv) * scl);
                }
            }
        }
    } else {
        // ---- V epilogue: swapped orientation -> direct Vt [bh][d][t] ----
#pragma unroll
        for (int nt = 0; nt < 4; ++nt) {
            const int n_b = n0 + wn + nt * 16 + qd * 4;   // 4 consecutive d
            const float4 bv = *(const float4*)&bias[n_b];
            const int h = (n_b >> 6) & 15;
            const int d0 = n_b & 63;
#pragma unroll
            for (int mt = 0; mt < 4; ++mt) {
                const int m_g = m0 + wm + mt * 16 + l15;
                const int b = m_g >> 11, tt = m_g & 2047;
                const size_t rowb = (size_t)(b * Hn + h) * Dn;
                Vo[(rowb + d0 + 0) * Tn + tt] = f2bfu(acc[nt][mt][0] + bv.x);
                Vo[(rowb + d0 + 1) * Tn + tt] = f2bfu(acc[nt][mt][1] + bv.y);
                Vo[(rowb + d0 + 2) * Tn + tt] = f2bfu(acc[nt][mt][2] + bv.z);
                Vo[(rowb + d0 + 3) * Tn + tt] = f2bfu(acc[nt][mt][3] + bv.w);
            }
        }
    }
}

// ---------------------------------------------------------------------------
// MFMA flash attention (r8-proven, ~88us): async-DMA pipelined K/Vt LDS
// double-buffer, source-side swizzle, transposed-S, exp2 softmax, VALU-diet
// online softmax (defer-max THR=8 — running max makes it input-scale-safe;
// r12 proved fixed-scale diverges on the harness's timing inputs),
// packed f32 ops, deferred l reduction, setprio on MFMA.
// ---------------------------------------------------------------------------
__global__ __launch_bounds__(256, 4) void attn_mfma(
    const ushort* __restrict__ Q, const ushort* __restrict__ K,
    const ushort* __restrict__ Vt, ushort* __restrict__ Y)
{
    __shared__ __align__(16) ushort Ks[2][64 * 64];
    __shared__ __align__(16) ushort Vs[2][64 * 64];
    __shared__ __align__(16) ushort Ps[64 * 64];

    const int tid = threadIdx.x;
    const int bh = blockIdx.x, bx = blockIdx.y;
    const int w = tid >> 6, lane = tid & 63, l15 = lane & 15, qd = lane >> 4;
    const size_t base = (size_t)bh * Tn * Dn;
    const int lrow = lane >> 3;                   // 0..7
    const int lchunk = (lane & 7) ^ (lrow & 7);   // source-side swizzle
    const int q_l = w * 16 + l15;
    const int frow = q_l * 64;
    const int fx0 = ((0 * 4 + qd) ^ (l15 & 7)) * 8;
    const int fx1 = ((1 * 4 + qd) ^ (l15 & 7)) * 8;
    const int b = bh >> 4, h = bh & 15;

    // staging sources: wave w stages rows w*16 .. w*16+15 of each tile
    const ushort* Kg = K + base + (size_t)(w * 16 + lrow) * Dn + lchunk * 8;
    const ushort* Vg = Vt + base + (size_t)(w * 16 + lrow) * Tn + lchunk * 8;
    // Q fragments direct from global
    const ushort* Qp = Q + base + (size_t)l15 * Dn + qd * 8;

#pragma unroll
    for (int half = 0; half < 2; ++half) {
        const int qt = half ? (31 - bx) : bx;

        const ushort* qrow = Qp + (size_t)(qt * 64 + w * 16) * Dn;
        s16x8 qf0 = *(const s16x8*)(qrow);
        s16x8 qf1 = *(const s16x8*)(qrow + 32);

        __syncthreads();   // previous half's LDS reads complete
        // issue DMA for tile 0 -> buffer 0
#pragma unroll
        for (int t = 0; t < 2; ++t) {
            gl_lds16(Kg + (size_t)(t * 8) * Dn, &Ks[0][(w * 16 + t * 8) * 64]);
            gl_lds16(Vg + (size_t)(t * 8) * Tn, &Vs[0][(w * 16 + t * 8) * 64]);
        }

        float m_run = -1e30f, l_run = 0.f;   // l_run: per-lane partial sum
        f32x4 o[4] = {};   // O^T[d=dt*16+qd*4+r][q=l15]

        for (int kt = 0; kt <= qt; ++kt) {
            const int buf = kt & 1;
            __syncthreads();   // drains own vmcnt -> tile kt ready; buf^1 free
            if (kt < qt) {     // issue DMA for kt+1 -> buf^1 (overlaps compute)
#pragma unroll
                for (int t = 0; t < 2; ++t) {
                    gl_lds16(Kg + (size_t)((kt + 1) * 64 + t * 8) * Dn,
                             &Ks[buf ^ 1][(w * 16 + t * 8) * 64]);
                    gl_lds16(Vg + (size_t)(t * 8) * Tn + (kt + 1) * 64,
                             &Vs[buf ^ 1][(w * 16 + t * 8) * 64]);
                }
            }

            // S^T = K·Q^T (exp2 domain via pre-scaled Q)
            f32x4 s[4] = {};
            __builtin_amdgcn_s_setprio(1);
#pragma unroll
            for (int nt = 0; nt < 4; ++nt) {
                s16x8 kf = *(const s16x8*)&Ks[buf][(nt * 16 + l15) * 64 + fx0];
                s[nt] = MFMA_BF16(kf, qf0, s[nt]);
            }
#pragma unroll
            for (int nt = 0; nt < 4; ++nt) {
                s16x8 kf = *(const s16x8*)&Ks[buf][(nt * 16 + l15) * 64 + fx1];
                s[nt] = MFMA_BF16(kf, qf1, s[nt]);
            }
            __builtin_amdgcn_s_setprio(0);

            if (kt == qt) {
#pragma unroll
                for (int nt = 0; nt < 4; ++nt)
#pragma unroll
                    for (int r = 0; r < 4; ++r)
                        if (nt * 16 + qd * 4 + r > q_l) s[nt][r] = -1e30f;
            }

            // per-query max: depth-4 tree (fuses to v_max3) + 2 shuffles
            float a0 = fmaxf(fmaxf(s[0][0], s[0][1]), fmaxf(s[0][2], s[0][3]));
            float a1 = fmaxf(fmaxf(s[1][0], s[1][1]), fmaxf(s[1][2], s[1][3]));
            float a2 = fmaxf(fmaxf(s[2][0], s[2][1]), fmaxf(s[2][2], s[2][3]));
            float a3 = fmaxf(fmaxf(s[3][0], s[3][1]), fmaxf(s[3][2], s[3][3]));
            float mx = fmaxf(fmaxf(a0, a1), fmaxf(a2, a3));
            mx = fmaxf(mx, __shfl_xor(mx, 16));
            mx = fmaxf(mx, __shfl_xor(mx, 32));

            // defer-max: only rescale when the max grew by > 8 (2^8 bound)
            if (!__all(mx <= m_run + 8.f)) {
                float m_new = fmaxf(m_run, mx);
                float alpha = exp2f(m_run - m_new);
                m_run = m_new;
                l_run *= alpha;
                f32x2 aa = {alpha, alpha};
#pragma unroll
                for (int dt = 0; dt < 4; ++dt) {
                    o[dt].lo = pk_mul(o[dt].lo, aa);
                    o[dt].hi = pk_mul(o[dt].hi, aa);
                }
            }

            // p = exp2(s - m_run); packed subtract / packed l-accum
            const f32x2 negm = {-m_run, -m_run};
            f32x2 lac0 = {0.f, 0.f}, lac1 = {0.f, 0.f};
#pragma unroll
            for (int nt = 0; nt < 4; ++nt) {
                s[nt].lo = pk_add(s[nt].lo, negm);
                s[nt].hi = pk_add(s[nt].hi, negm);
                s[nt][0] = exp2f(s[nt][0]);
                s[nt][1] = exp2f(s[nt][1]);
                s[nt][2] = exp2f(s[nt][2]);
                s[nt][3] = exp2f(s[nt][3]);
                lac0 = pk_add(lac0, s[nt].lo);
                lac1 = pk_add(lac1, s[nt].hi);
            }
            lac0 = pk_add(lac0, lac1);
            l_run += lac0[0] + lac0[1];

            // P^T -> wave-private LDS rows (packed bf16 pairs)
#pragma unroll
            for (int nt = 0; nt < 4; ++nt) {
                uint2 pk;
                pk.x = pkbf(s[nt][0], s[nt][1]);
                pk.y = pkbf(s[nt][2], s[nt][3]);
                const int pc = 2 * nt + (qd >> 1), po = (qd & 1) * 4;
                *(uint2*)&Ps[frow + ((pc ^ (l15 & 7)) * 8) + po] = pk;
            }

            // O^T += V^T · P^T  (same-wave LDS round trip; no barrier)
            {
                s16x8 pb = *(const s16x8*)&Ps[frow + fx0];
                __builtin_amdgcn_s_setprio(1);
#pragma unroll
                for (int dt = 0; dt < 4; ++dt) {
                    s16x8 vf = *(const s16x8*)&Vs[buf][(dt * 16 + l15) * 64 + fx0];
                    o[dt] = MFMA_BF16(vf, pb, o[dt]);
                }
                pb = *(const s16x8*)&Ps[frow + fx1];
#pragma unroll
                for (int dt = 0; dt < 4; ++dt) {
                    s16x8 vf = *(const s16x8*)&Vs[buf][(dt * 16 + l15) * 64 + fx1];
                    o[dt] = MFMA_BF16(vf, pb, o[dt]);
                }
                __builtin_amdgcn_s_setprio(0);
            }
        }

        // epilogue: reduce partial l across the 4-lane query group, then
        // O^T[d][q=l15] -> Y[b, t=q_global, h*64+d]
        float lt = l_run;
        lt += __shfl_xor(lt, 16);
        lt += __shfl_xor(lt, 32);
        const float inv = 1.f / lt;
        const int t_g = qt * 64 + w * 16 + l15;
        ushort* yp = Y + ((size_t)(b * Tn + t_g)) * Cn + h * Dn + qd * 4;
#pragma unroll
        for (int dt = 0; dt < 4; ++dt) {
            uint2 pk;
            pk.x = pkbf(o[dt][0] * inv, o[dt][1] * inv);
            pk.y = pkbf(o[dt][2] * inv, o[dt][3] * inv);
            *(uint2*)(yp + dt * 16) = pk;
        }
    }
}

// ---------------------------------------------------------------------------
// Proj GEMM, pipelined (r8-proven, 2D grid): Y [8192][1024] bf16,
// Wt [1024][1024] bf16 -> out fp32
// ---------------------------------------------------------------------------
__global__ __launch_bounds__(256, 2) void proj_gemm_mfma(
    const ushort* __restrict__ A, const ushort* __restrict__ Bt,
    const float* __restrict__ bias, float* __restrict__ out)
{
    __shared__ __align__(16) ushort As[2][128 * 64];
    __shared__ __align__(16) ushort Bs[2][128 * 64];
    const int tid = threadIdx.x;
    const int m0 = blockIdx.x * 128, n0 = blockIdx.y * 128;
    const int w = tid >> 6, lane = tid & 63, l15 = lane & 15, qd = lane >> 4;
    const int wm = (w >> 1) * 64, wn = (w & 1) * 64;
    const int lrow = lane >> 3;
    const int lchunk = (lane & 7) ^ (lrow & 7);

    const ushort* gA = A + (size_t)(m0 + w * 32 + lrow) * Cn + lchunk * 8;
    const ushort* gB = Bt + (size_t)(n0 + w * 32 + lrow) * Cn + lchunk * 8;

    f32x4 acc[4][4] = {};

    GSTAGE(0, 0);
    GSTAGE(1, 1);

    for (int s = 0; s < 16; ++s) {
        if (s < 15) { asm volatile("s_waitcnt vmcnt(8)" ::: "memory"); }
        else        { asm volatile("s_waitcnt vmcnt(0)" ::: "memory"); }
        __builtin_amdgcn_sched_barrier(0);
        __builtin_amdgcn_s_barrier();
        __builtin_amdgcn_sched_barrier(0);

        const ushort* a_ = As[s & 1];
        const ushort* b_ = Bs[s & 1];
        __builtin_amdgcn_s_setprio(1);
#pragma unroll
        for (int ks = 0; ks < 2; ++ks) {
            const int xs = (((ks * 4 + qd) ^ (l15 & 7))) * 8;
            s16x8 af[4], bfr[4];
#pragma unroll
            for (int i = 0; i < 4; ++i) {
                af[i]  = *(const s16x8*)&a_[(wm + i * 16 + l15) * 64 + xs];
                bfr[i] = *(const s16x8*)&b_[(wn + i * 16 + l15) * 64 + xs];
            }
#pragma unroll
            for (int mt = 0; mt < 4; ++mt)
#pragma unroll
                for (int nt = 0; nt < 4; ++nt)
                    acc[mt][nt] = MFMA_BF16(af[mt], bfr[nt], acc[mt][nt]);
        }
        __builtin_amdgcn_s_setprio(0);

        __builtin_amdgcn_sched_barrier(0);
        __builtin_amdgcn_s_barrier();
        __builtin_amdgcn_sched_barrier(0);
        if (s + 2 < 16) { GSTAGE(s + 2, s & 1); }
    }

#pragma unroll
    for (int nt = 0; nt < 4; ++nt) {
        int n_g = n0 + wn + nt * 16 + l15;
        float bv = bias[n_g];
#pragma unroll
        for (int mt = 0; mt < 4; ++mt) {
#pragma unroll
            for (int r = 0; r < 4; ++r) {
                int m_g = m0 + wm + mt * 16 + qd * 4 + r;
                out[(size_t)m_g * Cn + n_g] = acc[mt][nt][r] + bv;
            }
        }
    }
}

// ---------------------------------------------------------------------------
extern "C" void kernel_launch(void* const* d_in, const int* in_sizes, int n_in,
                              void* d_out, int out_size, void* d_ws, size_t ws_size,
                              hipStream_t stream) {
    const float* x      = (const float*)d_in[0];
    const float* W_attn = (const float*)d_in[1];
    const float* b_attn = (const float*)d_in[2];
    const float* W_proj = (const float*)d_in[3];
    const float* b_proj = (const float*)d_in[4];
    float* out = (float*)d_out;

    // ws: Q, K [B,H,T,D] bf16; Vt [B,H,D,T] bf16 (written directly by qkv);
    //     Y [B,T,C] bf16
    constexpr size_t PER = (size_t)Mn * Cn;  // 8388608 elems
    ushort* Qb  = (ushort*)d_ws;
    ushort* Kb  = Qb + PER;
    ushort* Vtb = Kb + PER;
    ushort* Yb  = Vtb + PER;

    // d_out as scratch (33.5 MB): WtA [3072][1024] bf16 + x_bf [8192][1024] bf16
    ushort* WtA  = (ushort*)d_out;
    ushort* x_bf = WtA + (size_t)Nqkv * Cn;
    ushort* WtP  = Qb;                 // reuses Q buffer (dead after attention)

    prep_kernel<<<2816, 256, 0, stream>>>(x, x_bf, (int)(PER / 4), W_attn, WtA);
    qkv_gemm_mfma<<<dim3(Mn / 128, Nqkv / 128), 256, 0, stream>>>(
        x_bf, WtA, b_attn, Qb, Kb, Vtb);
    attn_mfma<<<dim3(Bn * Hn, 16), 256, 0, stream>>>(Qb, Kb, Vtb, Yb);
    transpose_cvt_kernel<<<dim3(Cn / 64, Cn / 64), 256, 0, stream>>>(
        W_proj, WtP, Cn, Cn);
    proj_gemm_mfma<<<dim3(Mn / 128, Cn / 128), 256, 0, stream>>>(
        Yb, WtP, b_proj, out);
}